// Round 3
// baseline (336.469 us; speedup 1.0000x reference)
//
#include <hip/hip_runtime.h>
#include <hip/hip_cooperative_groups.h>

namespace cg = cooperative_groups;

#define BLOCK 256
#define GRID_BLOCKS 1024
#define NPANEL 8
#define RCHUNK 16

// Single fused cooperative kernel.
// Phase A: row L1 sums -> scale[b] = W[b]/R[b]; zero out[].
//          All 1024 blocks co-resident sweep rows LEFT->RIGHT, so at the end
//          the RIGHTMOST ~256MB of columns is Infinity-Cache resident.
// grid.sync()
// Phase B: column sums, processed in 8 column-panels RIGHT->LEFT in time, so
//          the L3-resident panels are consumed while still hot.
__global__ __launch_bounds__(BLOCK, 4) void fused_kernel(
    const float* __restrict__ weights, const float* __restrict__ W,
    float* __restrict__ out, float* __restrict__ scale, int B, int C) {
  const int n4 = C >> 2;
  const int g = blockIdx.x * BLOCK + threadIdx.x;
  const int nthreads = gridDim.x * BLOCK;

  // Zero the output (poisoned by harness; phase B accumulates atomically).
  for (int c = g; c < C; c += nthreads) out[c] = 0.f;

  // ---- Phase A: row sums -> scale ----
  for (int b = blockIdx.x; b < B; b += gridDim.x) {
    const float* row = weights + (size_t)b * (size_t)C;
    const float4* row4 = reinterpret_cast<const float4*>(row);
    float acc = 0.f;
    for (int i = threadIdx.x; i < n4; i += BLOCK) {
      float4 v = row4[i];
      acc += fabsf(v.x) + fabsf(v.y) + fabsf(v.z) + fabsf(v.w);
    }
    // generic tail (empty for C % 4 == 0)
    for (int c = (n4 << 2) + threadIdx.x; c < C; c += BLOCK)
      acc += fabsf(row[c]);
#pragma unroll
    for (int off = 32; off > 0; off >>= 1) acc += __shfl_down(acc, off, 64);
    __shared__ float red[BLOCK / 64];
    if ((threadIdx.x & 63) == 0) red[threadIdx.x >> 6] = acc;
    __syncthreads();
    if (threadIdx.x == 0) {
      float t = 0.f;
#pragma unroll
      for (int w = 0; w < BLOCK / 64; ++w) t += red[w];
      scale[b] = W[b] / t;
    }
    __syncthreads();
  }

  cg::this_grid().sync();

  // ---- Phase B: weighted column sums, panels right->left ----
  const int PF4 = (n4 + NPANEL - 1) / NPANEL;      // f4-columns per panel
  const int nrc = (B + RCHUNK - 1) / RCHUNK;       // row chunks (64)
  for (int p = NPANEL - 1; p >= 0; --p) {
    int c4base = p * PF4;
    int pw = n4 - c4base;
    if (pw <= 0) continue;
    if (pw > PF4) pw = PF4;
    long items = (long)pw * (long)nrc;
    if ((long)g < items) {
      int c4 = c4base + (int)((long)g % (long)pw);
      int rc = (int)((long)g / (long)pw);
      int b0 = rc * RCHUNK;
      int b1 = min(B, b0 + RCHUNK);
      const float4* wp =
          reinterpret_cast<const float4*>(weights) + (size_t)b0 * (size_t)n4 + c4;
      float4 acc = make_float4(0.f, 0.f, 0.f, 0.f);
      for (int bb = b0; bb < b1; ++bb, wp += n4) {
        float4 v = *wp;
        float s = scale[bb];
        acc.x = fmaf(s, fabsf(v.x), acc.x);
        acc.y = fmaf(s, fabsf(v.y), acc.y);
        acc.z = fmaf(s, fabsf(v.z), acc.z);
        acc.w = fmaf(s, fabsf(v.w), acc.w);
      }
      int c = c4 << 2;
      atomicAdd(&out[c + 0], acc.x);
      atomicAdd(&out[c + 1], acc.y);
      atomicAdd(&out[c + 2], acc.z);
      atomicAdd(&out[c + 3], acc.w);
    }
  }

  // Scalar tail columns (empty for C % 4 == 0); single writer -> plain store.
  for (int c = (n4 << 2) + g; c < C; c += nthreads) {
    float acc = 0.f;
    for (int bb = 0; bb < B; ++bb)
      acc = fmaf(scale[bb], fabsf(weights[(size_t)bb * (size_t)C + c]), acc);
    out[c] = acc;
  }
}

extern "C" void kernel_launch(void* const* d_in, const int* in_sizes, int n_in,
                              void* d_out, int out_size, void* d_ws, size_t ws_size,
                              hipStream_t stream) {
  const float* W = (const float*)d_in[0];
  const float* weights = (const float*)d_in[1];
  float* out = (float*)d_out;
  float* scale = (float*)d_ws;  // B floats of scratch

  int B = in_sizes[0];  // 1024
  int C = out_size;     // 100000

  void* args[] = {(void*)&weights, (void*)&W, (void*)&out, (void*)&scale,
                  (void*)&B, (void*)&C};
  hipLaunchCooperativeKernel((const void*)fused_kernel, dim3(GRID_BLOCKS),
                             dim3(BLOCK), args, 0, stream);
}

// Round 4
// 184.057 us; speedup vs baseline: 1.8281x; 1.8281x over previous
//
#include <hip/hip_runtime.h>

#define BLOCK 256
#define RCHUNK 16
#define NPANELS 6

// ---------------------------------------------------------------------------
// Pass 1: one block per row b. scale[b] = W[b] / sum_c |weights[b,c]|.
// 4 independent accumulators + unroll-4 to keep >=4 loads in flight per lane.
// All blocks sweep columns L->R simultaneously, so the RIGHTMOST ~256 MB of
// columns is Infinity-Cache resident when pass 2 starts.
// ---------------------------------------------------------------------------
__global__ __launch_bounds__(BLOCK, 4) void rowscale_kernel(
    const float* __restrict__ weights, const float* __restrict__ W,
    float* __restrict__ scale, int B, int C) {
  int b = blockIdx.x;
  if (b >= B) return;
  const float* row = weights + (size_t)b * (size_t)C;
  const int n4 = C >> 2;
  const float4* row4 = reinterpret_cast<const float4*>(row);
  float a0 = 0.f, a1 = 0.f, a2 = 0.f, a3 = 0.f;
  int i = threadIdx.x;
  for (; i + 3 * BLOCK < n4; i += 4 * BLOCK) {
    float4 v0 = row4[i];
    float4 v1 = row4[i + BLOCK];
    float4 v2 = row4[i + 2 * BLOCK];
    float4 v3 = row4[i + 3 * BLOCK];
    a0 += fabsf(v0.x) + fabsf(v0.y) + fabsf(v0.z) + fabsf(v0.w);
    a1 += fabsf(v1.x) + fabsf(v1.y) + fabsf(v1.z) + fabsf(v1.w);
    a2 += fabsf(v2.x) + fabsf(v2.y) + fabsf(v2.z) + fabsf(v2.w);
    a3 += fabsf(v3.x) + fabsf(v3.y) + fabsf(v3.z) + fabsf(v3.w);
  }
  for (; i < n4; i += BLOCK) {
    float4 v = row4[i];
    a0 += fabsf(v.x) + fabsf(v.y) + fabsf(v.z) + fabsf(v.w);
  }
  for (int c = (n4 << 2) + threadIdx.x; c < C; c += BLOCK) a0 += fabsf(row[c]);
  float acc = (a0 + a1) + (a2 + a3);
#pragma unroll
  for (int off = 32; off > 0; off >>= 1) acc += __shfl_down(acc, off, 64);
  __shared__ float red[BLOCK / 64];
  if ((threadIdx.x & 63) == 0) red[threadIdx.x >> 6] = acc;
  __syncthreads();
  if (threadIdx.x == 0) {
    float t = 0.f;
#pragma unroll
    for (int w = 0; w < BLOCK / 64; ++w) t += red[w];
    scale[b] = W[b] / t;
  }
}

// ---------------------------------------------------------------------------
// Pass 2: partial weighted column sums. NO atomics, NO redundant VMEM:
// scale[] staged in LDS (DS pipe), so the ONLY VMEM instrs are the data loads.
// 1024 co-resident blocks grid-stride through 6 column panels RIGHT->LEFT in
// program order -> temporal ordering without grid.sync: hot (rightmost)
// panels consumed first; pass ends leftmost so next replay's pass 1 hits too.
// partial[rc][c] chunk stride is 4*n4 floats (vector part only).
// ---------------------------------------------------------------------------
__global__ __launch_bounds__(BLOCK, 4) void colsum_partial_kernel(
    const float* __restrict__ weights, const float* __restrict__ scale,
    float* __restrict__ partial, int B, int C) {
  __shared__ float s_scale[2048];
  const int n4 = C >> 2;
  const int nrc = (B + RCHUNK - 1) / RCHUNK;
  const bool inlds = (B <= 2048);
  if (inlds)
    for (int i = threadIdx.x; i < B; i += BLOCK) s_scale[i] = scale[i];
  __syncthreads();

  const long g = (long)blockIdx.x * BLOCK + threadIdx.x;
  const long nthreads = (long)gridDim.x * BLOCK;
  const float4* w4 = reinterpret_cast<const float4*>(weights);
  float4* p4 = reinterpret_cast<float4*>(partial);
  const int pw = (n4 + NPANELS - 1) / NPANELS;

  for (int p = NPANELS - 1; p >= 0; --p) {
    const int c4lo = p * pw;
    int c4hi = c4lo + pw;
    if (c4hi > n4) c4hi = n4;
    const int w = c4hi - c4lo;
    if (w <= 0) continue;
    const long items = (long)w * (long)nrc;
    for (long it = g; it < items; it += nthreads) {
      const int c4 = c4lo + (int)(it % (long)w);
      const int rc = (int)(it / (long)w);
      const int b0 = rc * RCHUNK;
      float4 acc = make_float4(0.f, 0.f, 0.f, 0.f);
      const float4* wp = w4 + (size_t)b0 * (size_t)n4 + c4;
      if (b0 + RCHUNK <= B) {
#pragma unroll
        for (int j = 0; j < RCHUNK; ++j) {
          float4 v = wp[(size_t)j * (size_t)n4];
          float s = inlds ? s_scale[b0 + j] : scale[b0 + j];
          acc.x = fmaf(s, fabsf(v.x), acc.x);
          acc.y = fmaf(s, fabsf(v.y), acc.y);
          acc.z = fmaf(s, fabsf(v.z), acc.z);
          acc.w = fmaf(s, fabsf(v.w), acc.w);
        }
      } else {
        for (int bb = b0; bb < B; ++bb) {
          float4 v = wp[(size_t)(bb - b0) * (size_t)n4];
          float s = inlds ? s_scale[bb] : scale[bb];
          acc.x = fmaf(s, fabsf(v.x), acc.x);
          acc.y = fmaf(s, fabsf(v.y), acc.y);
          acc.z = fmaf(s, fabsf(v.z), acc.z);
          acc.w = fmaf(s, fabsf(v.w), acc.w);
        }
      }
      p4[(size_t)rc * (size_t)n4 + c4] = acc;
    }
  }
}

// ---------------------------------------------------------------------------
// Pass 3: out[c] = sum_k partial[k][c] for vector columns; tail columns
// (C%4 != 0) computed directly from weights (empty for C = 100000).
// Plain stores overwrite harness poison.
// ---------------------------------------------------------------------------
__global__ __launch_bounds__(BLOCK) void reduce_partials_kernel(
    const float* __restrict__ partial, const float* __restrict__ weights,
    const float* __restrict__ scale, float* __restrict__ out, int B, int C) {
  const int n4 = C >> 2;
  const int nrc = (B + RCHUNK - 1) / RCHUNK;
  const size_t pstride = (size_t)(n4 << 2);
  int c = blockIdx.x * BLOCK + threadIdx.x;
  if (c < (n4 << 2)) {
    float s = 0.f;
    for (int k = 0; k < nrc; ++k) s += partial[(size_t)k * pstride + c];
    out[c] = s;
  }
  const int tail0 = n4 << 2;
  if (tail0 < C && blockIdx.x == 0) {
    for (int cc = tail0 + threadIdx.x; cc < C; cc += BLOCK) {
      float acc = 0.f;
      for (int bb = 0; bb < B; ++bb)
        acc = fmaf(scale[bb], fabsf(weights[(size_t)bb * (size_t)C + cc]), acc);
      out[cc] = acc;
    }
  }
}

extern "C" void kernel_launch(void* const* d_in, const int* in_sizes, int n_in,
                              void* d_out, int out_size, void* d_ws, size_t ws_size,
                              hipStream_t stream) {
  const float* W = (const float*)d_in[0];
  const float* weights = (const float*)d_in[1];
  float* out = (float*)d_out;
  float* scale = (float*)d_ws;                          // B floats
  float* partial = (float*)((char*)d_ws + 4096);        // nrc * 4*n4 floats

  int B = in_sizes[0];  // 1024
  int C = out_size;     // 100000

  // Pass 1: row scales.
  rowscale_kernel<<<B, BLOCK, 0, stream>>>(weights, W, scale, B, C);

  // Pass 2: partial column sums (1024 co-resident blocks, panels R->L).
  colsum_partial_kernel<<<1024, BLOCK, 0, stream>>>(weights, scale, partial, B, C);

  // Pass 3: reduce partials + tail columns.
  int n4 = C >> 2;
  int rblocks = ((n4 << 2) + BLOCK - 1) / BLOCK;
  if (rblocks < 1) rblocks = 1;
  reduce_partials_kernel<<<rblocks, BLOCK, 0, stream>>>(partial, weights, scale,
                                                        out, B, C);
}